// Round 1
// baseline (394.367 us; speedup 1.0000x reference)
//
#include <hip/hip_runtime.h>
#include <hip/hip_bf16.h>
#include <stdint.h>

// TernaryLinear: out = scale * (x_bf16 @ wq_bf16^T), scale = mean|W|+1e-8
// M=8192 (4*2048), K=2048, N=8192. Inputs fp32, output fp32.
//
// Workspace layout (needs 8192 + 2*33554432 = ~64MB):
//   [0      .. 4096)   : 1024 fp32 block partial sums of |W|
//   [4096   .. 4100)   : fp32 scale
//   [8192   .. +32MB)  : Xb  bf16 [8192][2048]
//   [+32MB  .. +64MB)  : Wb  bf16 [8192][2048] (ternary * implicit scale)

typedef __attribute__((ext_vector_type(8))) short   s16x8;  // 8 bf16 in 4 VGPRs
typedef __attribute__((ext_vector_type(4))) float   f32x4;

#define K_DIM   2048
#define M_DIM   8192
#define N_DIM   8192
#define NELEM   16777216   // 8192*2048 (both X and W)
#define N4      4194304    // NELEM/4

// ---------------- scale reduction ----------------
__global__ void k_abs_part(const float4* __restrict__ w4, float* __restrict__ part) {
    int tid = blockIdx.x * 256 + threadIdx.x;
    float s = 0.f;
    for (int i = tid; i < N4; i += gridDim.x * 256) {
        float4 v = w4[i];
        s += fabsf(v.x) + fabsf(v.y) + fabsf(v.z) + fabsf(v.w);
    }
    for (int off = 32; off > 0; off >>= 1) s += __shfl_down(s, off, 64);
    __shared__ float tmp[4];
    int lane = threadIdx.x & 63, wid = threadIdx.x >> 6;
    if (lane == 0) tmp[wid] = s;
    __syncthreads();
    if (threadIdx.x == 0) part[blockIdx.x] = tmp[0] + tmp[1] + tmp[2] + tmp[3];
}

__global__ void k_abs_final(const float* __restrict__ part, float* __restrict__ scale) {
    // 1 block x 256 threads reduces 1024 partials, fixed order -> deterministic
    float s = part[threadIdx.x] + part[threadIdx.x + 256] +
              part[threadIdx.x + 512] + part[threadIdx.x + 768];
    for (int off = 32; off > 0; off >>= 1) s += __shfl_down(s, off, 64);
    __shared__ float tmp[4];
    int lane = threadIdx.x & 63, wid = threadIdx.x >> 6;
    if (lane == 0) tmp[wid] = s;
    __syncthreads();
    if (threadIdx.x == 0) scale[0] = (tmp[0] + tmp[1] + tmp[2] + tmp[3]) / 16777216.0f + 1e-8f;
}

// ---------------- quantize W -> ternary bf16 bits ----------------
__global__ void k_quant_w(const float4* __restrict__ w4, const float* __restrict__ scale_p,
                          uint2* __restrict__ wq) {
    const float sc = *scale_p;
    int tid = blockIdx.x * 256 + threadIdx.x;
    for (int i = tid; i < N4; i += gridDim.x * 256) {
        float4 v = w4[i];
        // rintf = round-half-even, matches jnp.round; IEEE divide matches reference
        float q0 = rintf(v.x / sc), q1 = rintf(v.y / sc), q2 = rintf(v.z / sc), q3 = rintf(v.w / sc);
        uint32_t b0 = (q0 == 0.f) ? 0u : (q0 > 0.f ? 0x3F80u : 0xBF80u);
        uint32_t b1 = (q1 == 0.f) ? 0u : (q1 > 0.f ? 0x3F80u : 0xBF80u);
        uint32_t b2 = (q2 == 0.f) ? 0u : (q2 > 0.f ? 0x3F80u : 0xBF80u);
        uint32_t b3 = (q3 == 0.f) ? 0u : (q3 > 0.f ? 0x3F80u : 0xBF80u);
        uint2 o; o.x = b0 | (b1 << 16); o.y = b2 | (b3 << 16);
        wq[i] = o;
    }
}

// ---------------- convert X -> bf16 (RNE) ----------------
__device__ __forceinline__ uint32_t f2b(float f) {
    uint32_t u = __builtin_bit_cast(uint32_t, f);
    return (u + 0x7FFFu + ((u >> 16) & 1u)) >> 16;  // RNE, no NaN in input
}
__global__ void k_conv_x(const float4* __restrict__ x4, uint2* __restrict__ xb) {
    int tid = blockIdx.x * 256 + threadIdx.x;
    for (int i = tid; i < N4; i += gridDim.x * 256) {
        float4 v = x4[i];
        uint2 o;
        o.x = f2b(v.x) | (f2b(v.y) << 16);
        o.y = f2b(v.z) | (f2b(v.w) << 16);
        xb[i] = o;
    }
}

// ---------------- GEMM ----------------
// 128x128 tile, BK=64, 256 threads = 4 waves (2x2), each wave 64x64 out (4x4 frags
// of 16x16). LDS: A[128][64] bf16 + B[128][64] bf16 = 32KB, XOR-swizzled
// (16B-slot ^= row&7) via pre-swizzled global_load_lds source + swizzled ds_read.

__device__ __forceinline__ void mfma16(f32x4& c, s16x8 a, s16x8 b) {
    asm("v_mfma_f32_16x16x32_bf16 %0, %1, %2, %0" : "+v"(c) : "v"(a), "v"(b));
}

__device__ __forceinline__ void load_lds16(const void* g, void* l) {
    __builtin_amdgcn_global_load_lds(
        (const __attribute__((address_space(1))) uint32_t*)g,
        (__attribute__((address_space(3))) uint32_t*)l, 16, 0, 0);
}

__global__ __launch_bounds__(256) void k_gemm(
    const unsigned short* __restrict__ Xb,   // [8192][2048] bf16 bits
    const unsigned short* __restrict__ Wb,   // [8192][2048] bf16 bits
    const float* __restrict__ scale_p,
    float* __restrict__ out)                 // [8192][8192] fp32
{
    __shared__ uint4 lds[2048];              // 32KB: A at byte 0, B at byte 16384
    const int tid  = threadIdx.x;
    const int lane = tid & 63;
    const int wid  = tid >> 6;               // 0..3
    const int wrow = wid >> 1, wcol = wid & 1;

    // XCD-aware bijective swizzle (4096 % 8 == 0)
    int bid = blockIdx.x;
    int swz = (bid & 7) * 512 + (bid >> 3);
    const int tileRow = swz >> 6;            // 0..63
    const int tileCol = swz & 63;

    // staging: per-lane pre-swizzled source. phys LDS P = chunk*1024 + lane*16.
    // logical L = P ^ ((lane>>3)<<4): row = chunk*8 + (lane>>3),
    // colByte = 16*((lane&7) ^ (lane>>3)).
    const int lrow  = lane >> 3;                       // 0..7
    const int lcolE = (((lane & 7) ^ lrow) << 4) >> 1; // swizzled col in bf16 elems
    const unsigned short* gA = Xb + (size_t)tileRow * 128 * K_DIM;
    const unsigned short* gB = Wb + (size_t)tileCol * 128 * K_DIM;
    uint8_t* ldsb = (uint8_t*)lds;

    f32x4 acc[4][4] = {};

    for (int kt = 0; kt < K_DIM / 64; ++kt) {
        const int k0 = kt * 64;
        __syncthreads();  // previous compute done before overwrite
        #pragma unroll
        for (int c = 0; c < 4; ++c) {
            const int chunk = wid * 4 + c;                     // wave-uniform
            const int row   = chunk * 8 + lrow;                // 0..127
            load_lds16(gA + (size_t)row * K_DIM + k0 + lcolE, ldsb + chunk * 1024);
            load_lds16(gB + (size_t)row * K_DIM + k0 + lcolE, ldsb + 16384 + chunk * 1024);
        }
        __syncthreads();  // compiler drains vmcnt before barrier -> LDS visible

        const uint8_t* ldsA = ldsb;
        const uint8_t* ldsB = ldsb + 16384;
        #pragma unroll
        for (int kc = 0; kc < 2; ++kc) {
            s16x8 af[4], bfr[4];
            #pragma unroll
            for (int m = 0; m < 4; ++m) {
                int r    = wrow * 64 + m * 16 + (lane & 15);
                int colb = (kc * 64 + ((lane >> 4) << 4)) ^ ((r & 7) << 4);
                af[m] = *(const s16x8*)(ldsA + r * 128 + colb);
            }
            #pragma unroll
            for (int n = 0; n < 4; ++n) {
                int r    = wcol * 64 + n * 16 + (lane & 15);
                int colb = (kc * 64 + ((lane >> 4) << 4)) ^ ((r & 7) << 4);
                bfr[n] = *(const s16x8*)(ldsB + r * 128 + colb);
            }
            #pragma unroll
            for (int m = 0; m < 4; ++m)
                #pragma unroll
                for (int n = 0; n < 4; ++n)
                    mfma16(acc[m][n], af[m], bfr[n]);
        }
    }

    // epilogue: C[row][col], col = lane&15, row = (lane>>4)*4 + j  (m89/m91 layout)
    const float sc = *scale_p;
    const int orow0 = tileRow * 128 + wrow * 64;
    const int ocol0 = tileCol * 128 + wcol * 64;
    #pragma unroll
    for (int m = 0; m < 4; ++m) {
        const int rbase = orow0 + m * 16 + ((lane >> 4) << 2);
        #pragma unroll
        for (int n = 0; n < 4; ++n) {
            const int col = ocol0 + n * 16 + (lane & 15);
            #pragma unroll
            for (int j = 0; j < 4; ++j)
                out[(size_t)(rbase + j) * N_DIM + col] = acc[m][n][j] * sc;
        }
    }
}

// ---------------- launch ----------------
extern "C" void kernel_launch(void* const* d_in, const int* in_sizes, int n_in,
                              void* d_out, int out_size, void* d_ws, size_t ws_size,
                              hipStream_t stream) {
    const float* x = (const float*)d_in[0];
    const float* w = (const float*)d_in[1];
    float* out = (float*)d_out;
    uint8_t* ws = (uint8_t*)d_ws;

    float* part  = (float*)ws;                       // 1024 floats
    float* scale = (float*)(ws + 4096);              // 1 float
    unsigned short* Xb = (unsigned short*)(ws + 8192);
    unsigned short* Wb = (unsigned short*)(ws + 8192 + 33554432ull);

    hipLaunchKernelGGL(k_abs_part, dim3(1024), dim3(256), 0, stream, (const float4*)w, part);
    hipLaunchKernelGGL(k_abs_final, dim3(1), dim3(256), 0, stream, part, scale);
    hipLaunchKernelGGL(k_quant_w, dim3(2048), dim3(256), 0, stream,
                       (const float4*)w, scale, (uint2*)Wb);
    hipLaunchKernelGGL(k_conv_x, dim3(2048), dim3(256), 0, stream,
                       (const float4*)x, (uint2*)Xb);
    hipLaunchKernelGGL(k_gemm, dim3(4096), dim3(256), 0, stream, Xb, Wb, scale, out);
}

// Round 2
// 329.371 us; speedup vs baseline: 1.1973x; 1.1973x over previous
//
#include <hip/hip_runtime.h>
#include <hip/hip_bf16.h>
#include <stdint.h>

// TernaryLinear: out = scale * (x_bf16 @ wq_bf16^T), scale = mean|W|+1e-8
// M=8192, K=2048, N=8192. fp32 in/out.
// GEMM: 256x256 tile, BK=64, 8 waves, 8-phase counted-vmcnt pipeline (m201 port).
//
// Stage/await ledger (iteration i, T=2i, T'=2i+1; buf0=even tiles, buf1=odd):
//   ph1: read Q0 frags buf0 (12 ds) | stage S(T',B-h0)->buf1.B   | MFMA Q0 m0-3 n0-1
//   ph2: read rest buf0 (12 ds)     | stage S(T',B-h1)           | MFMA Q1 m0-3 n2-3  [lgkm0 => buf0 read-complete]
//   ph3:                              stage S(T+2,A-h0)->buf0.A  | MFMA Q2 m4-7 n0-1
//   ph4:                              stage S(T+2,A-h1)          | MFMA Q3 m4-7 n2-3 | vmcnt(4): T' fully landed
//   ph5-8: mirror on buf1 / stage S(T+2,B-*), S(T+3,A-*)         | vmcnt(4) at ph8: T+2 landed
// Max 8 gloads in flight; awaited load was issued 2 phases prior. No vmcnt(0) in main loop.

typedef __attribute__((ext_vector_type(8))) short   s16x8;
typedef __attribute__((ext_vector_type(4))) float   f32x4;

#define K_DIM   2048
#define K2      4096        // row stride bytes (bf16)
#define N_DIM   8192
#define N4      4194304     // 8192*2048/4

// ---------------- scale reduction ----------------
__global__ void k_abs_part(const float4* __restrict__ w4, float* __restrict__ part) {
    int tid = blockIdx.x * 256 + threadIdx.x;
    float s = 0.f;
    for (int i = tid; i < N4; i += gridDim.x * 256) {
        float4 v = w4[i];
        s += fabsf(v.x) + fabsf(v.y) + fabsf(v.z) + fabsf(v.w);
    }
    for (int off = 32; off > 0; off >>= 1) s += __shfl_down(s, off, 64);
    __shared__ float tmp[4];
    int lane = threadIdx.x & 63, wid = threadIdx.x >> 6;
    if (lane == 0) tmp[wid] = s;
    __syncthreads();
    if (threadIdx.x == 0) part[blockIdx.x] = tmp[0] + tmp[1] + tmp[2] + tmp[3];
}

__global__ void k_abs_final(const float* __restrict__ part, float* __restrict__ scale) {
    float s = part[threadIdx.x] + part[threadIdx.x + 256] +
              part[threadIdx.x + 512] + part[threadIdx.x + 768];
    for (int off = 32; off > 0; off >>= 1) s += __shfl_down(s, off, 64);
    __shared__ float tmp[4];
    int lane = threadIdx.x & 63, wid = threadIdx.x >> 6;
    if (lane == 0) tmp[wid] = s;
    __syncthreads();
    if (threadIdx.x == 0) scale[0] = (tmp[0] + tmp[1] + tmp[2] + tmp[3]) / 16777216.0f + 1e-8f;
}

// ---------------- fused W-quant + X-convert ----------------
__device__ __forceinline__ uint32_t f2b(float f) {
    uint32_t u = __builtin_bit_cast(uint32_t, f);
    return (u + 0x7FFFu + ((u >> 16) & 1u)) >> 16;  // RNE
}

__global__ void k_prep(const float4* __restrict__ w4, const float4* __restrict__ x4,
                       const float* __restrict__ scale_p,
                       uint2* __restrict__ wq, uint2* __restrict__ xb) {
    int tid = (blockIdx.x & 2047) * 256 + threadIdx.x;
    if (blockIdx.x < 2048) {
        const float sc = *scale_p;
        for (int i = tid; i < N4; i += 2048 * 256) {
            float4 v = w4[i];
            float q0 = rintf(v.x / sc), q1 = rintf(v.y / sc);
            float q2 = rintf(v.z / sc), q3 = rintf(v.w / sc);
            uint32_t b0 = (q0 == 0.f) ? 0u : (q0 > 0.f ? 0x3F80u : 0xBF80u);
            uint32_t b1 = (q1 == 0.f) ? 0u : (q1 > 0.f ? 0x3F80u : 0xBF80u);
            uint32_t b2 = (q2 == 0.f) ? 0u : (q2 > 0.f ? 0x3F80u : 0xBF80u);
            uint32_t b3 = (q3 == 0.f) ? 0u : (q3 > 0.f ? 0x3F80u : 0xBF80u);
            uint2 o; o.x = b0 | (b1 << 16); o.y = b2 | (b3 << 16);
            wq[i] = o;
        }
    } else {
        for (int i = tid; i < N4; i += 2048 * 256) {
            float4 v = x4[i];
            uint2 o;
            o.x = f2b(v.x) | (f2b(v.y) << 16);
            o.y = f2b(v.z) | (f2b(v.w) << 16);
            xb[i] = o;
        }
    }
}

// ---------------- GEMM ----------------
__device__ __forceinline__ void mfma16(f32x4& c, s16x8 a, s16x8 b) {
    asm("v_mfma_f32_16x16x32_bf16 %0, %1, %2, %0" : "+v"(c) : "v"(a), "v"(b));
}
__device__ __forceinline__ void load_lds16(const void* g, void* l) {
    __builtin_amdgcn_global_load_lds(
        (const __attribute__((address_space(1))) uint32_t*)g,
        (__attribute__((address_space(3))) uint32_t*)l, 16, 0, 0);
}

#define SBAR do { __builtin_amdgcn_sched_barrier(0); __builtin_amdgcn_s_barrier(); \
                  __builtin_amdgcn_sched_barrier(0); } while (0)
#define LGKM0 do { asm volatile("s_waitcnt lgkmcnt(0)" ::: "memory"); \
                   __builtin_amdgcn_sched_barrier(0); } while (0)
#define WAIT_VM(N) do { asm volatile("s_waitcnt vmcnt(" #N ")" ::: "memory"); \
                        __builtin_amdgcn_sched_barrier(0); } while (0)

// LDS byte map (128 KiB): buf0.A=0, buf0.B=32768, buf1.A=65536, buf1.B=98304
#define A0_BASE 0
#define B0_BASE 32768
#define A1_BASE 65536
#define B1_BASE 98304

__global__ __launch_bounds__(512, 2) void k_gemm(
    const unsigned short* __restrict__ Xb,
    const unsigned short* __restrict__ Wb,
    const float* __restrict__ scale_p,
    float* __restrict__ out)
{
    extern __shared__ uint8_t smem[];
    const int tid  = threadIdx.x;
    const int lane = tid & 63;
    const int wid  = tid >> 6;
    const int wr   = wid >> 2;          // 0..1
    const int wc   = wid & 3;           // 0..3

    // XCD-aware bijective swizzle (1024 % 8 == 0)
    const int bid = blockIdx.x;
    const int swz = (bid & 7) * 128 + (bid >> 3);
    const int tileRow = swz >> 5;       // 0..31
    const int tileCol = swz & 31;

    const uint8_t* gA = (const uint8_t*)Xb + (size_t)tileRow * 256 * K2;
    const uint8_t* gB = (const uint8_t*)Wb + (size_t)tileCol * 256 * K2;

    // staging: thread t covers slot t and t+512 of a 128-row x 64-K half-region.
    // physical LDS slot c of row r holds global col-slot (c ^ (r&7))  (XOR swizzle).
    const int srow = tid >> 3, sslot = tid & 7;
    const size_t srcOff = (size_t)srow * K2 + (size_t)((sslot ^ (srow & 7)) * 16);
    const uint8_t* gAs = gA + srcOff;
    const uint8_t* gBs = gB + srcOff;
    const int dstOff = tid * 16;

    // LDS read bases (byte offsets); frag m adds m*2048 (16 rows * 128B)
    const int rA = wr * 128 + (lane & 15);
    const int rB = wc * 64  + (lane & 15);
    const int h  = lane >> 4;
    const int pA0 = rA * 128 + (((h    ) ^ (rA & 7)) * 16);
    const int pA1 = rA * 128 + (((4 + h) ^ (rA & 7)) * 16);
    const int pB0 = rB * 128 + (((h    ) ^ (rB & 7)) * 16);
    const int pB1 = rB * 128 + (((4 + h) ^ (rB & 7)) * 16);

    s16x8 a[8][2], b[4][2];
    f32x4 acc[8][4];
    #pragma unroll
    for (int m = 0; m < 8; ++m)
        #pragma unroll
        for (int n = 0; n < 4; ++n) acc[m][n] = (f32x4){0.f, 0.f, 0.f, 0.f};

#define LD8(OFF) (*(const s16x8*)(smem + (OFF)))
#define STAGE(LBASE, GP, BOFF) do { \
    load_lds16((GP) + (BOFF),          smem + (LBASE) + dstOff); \
    load_lds16((GP) + (BOFF) + 262144, smem + (LBASE) + 8192 + dstOff); } while (0)

#define READS_FIRST(ABASE) do { \
    _Pragma("unroll") for (int m = 0; m < 4; ++m) { \
        a[m][0] = LD8((ABASE) + pA0 + m * 2048); \
        a[m][1] = LD8((ABASE) + pA1 + m * 2048); } \
    _Pragma("unroll") for (int n = 0; n < 2; ++n) { \
        b[n][0] = LD8((ABASE) + 32768 + pB0 + n * 2048); \
        b[n][1] = LD8((ABASE) + 32768 + pB1 + n * 2048); } } while (0)

#define READS_SECOND(ABASE) do { \
    _Pragma("unroll") for (int n = 2; n < 4; ++n) { \
        b[n][0] = LD8((ABASE) + 32768 + pB0 + n * 2048); \
        b[n][1] = LD8((ABASE) + 32768 + pB1 + n * 2048); } \
    _Pragma("unroll") for (int m = 4; m < 8; ++m) { \
        a[m][0] = LD8((ABASE) + pA0 + m * 2048); \
        a[m][1] = LD8((ABASE) + pA1 + m * 2048); } } while (0)

#define MFMA_Q(MLO, NLO) do { \
    __builtin_amdgcn_s_setprio(1); \
    _Pragma("unroll") for (int kk = 0; kk < 2; ++kk) \
        _Pragma("unroll") for (int m = 0; m < 4; ++m) \
            _Pragma("unroll") for (int n = 0; n < 2; ++n) \
                mfma16(acc[(MLO) + m][(NLO) + n], a[(MLO) + m][kk], b[(NLO) + n][kk]); \
    __builtin_amdgcn_s_setprio(0); \
    __builtin_amdgcn_sched_barrier(0); } while (0)

    // prologue: T0 (all 4 halves) + T1 A-halves; await T0, leave T1.A in flight
    STAGE(A0_BASE,         gAs, 0);
    STAGE(A0_BASE + 16384, gAs, 524288);
    STAGE(B0_BASE,         gBs, 0);
    STAGE(B0_BASE + 16384, gBs, 524288);
    STAGE(A1_BASE,         gAs, 128);
    STAGE(A1_BASE + 16384, gAs, 524288 + 128);
    WAIT_VM(4);
    SBAR;

    #pragma unroll 1
    for (int i = 0; i < 15; ++i) {
        const int kb1 = (2 * i + 1) * 128;   // T' byte k-offset
        const int kb2 = kb1 + 128;           // T+2
        const int kb3 = kb1 + 256;           // T+3
        // ph1
        READS_FIRST(A0_BASE);
        STAGE(B1_BASE, gBs, kb1);
        SBAR; LGKM0; MFMA_Q(0, 0); SBAR;
        // ph2
        READS_SECOND(A0_BASE);
        STAGE(B1_BASE + 16384, gBs, 524288 + kb1);
        SBAR; LGKM0; MFMA_Q(0, 2); SBAR;
        // ph3
        STAGE(A0_BASE, gAs, kb2);
        SBAR; MFMA_Q(4, 0); SBAR;
        // ph4
        STAGE(A0_BASE + 16384, gAs, 524288 + kb2);
        SBAR; MFMA_Q(4, 2); WAIT_VM(4); SBAR;
        // ph5
        READS_FIRST(A1_BASE);
        STAGE(B0_BASE, gBs, kb2);
        SBAR; LGKM0; MFMA_Q(0, 0); SBAR;
        // ph6
        READS_SECOND(A1_BASE);
        STAGE(B0_BASE + 16384, gBs, 524288 + kb2);
        SBAR; LGKM0; MFMA_Q(0, 2); SBAR;
        // ph7
        STAGE(A1_BASE, gAs, kb3);
        SBAR; MFMA_Q(4, 0); SBAR;
        // ph8
        STAGE(A1_BASE + 16384, gAs, 524288 + kb3);
        SBAR; MFMA_Q(4, 2); WAIT_VM(4); SBAR;
    }

    // peeled last iteration (T=30, T'=31): stage only T31 B-halves, drain, no prefetch
    READS_FIRST(A0_BASE);
    STAGE(B1_BASE, gBs, 31 * 128);
    SBAR; LGKM0; MFMA_Q(0, 0); SBAR;
    READS_SECOND(A0_BASE);
    STAGE(B1_BASE + 16384, gBs, 524288 + 31 * 128);
    SBAR; LGKM0; MFMA_Q(0, 2); SBAR;
    MFMA_Q(4, 0);
    MFMA_Q(4, 2);
    WAIT_VM(0); SBAR;
    READS_FIRST(A1_BASE);
    SBAR; LGKM0; MFMA_Q(0, 0); SBAR;
    READS_SECOND(A1_BASE);
    SBAR; LGKM0; MFMA_Q(0, 2); SBAR;
    MFMA_Q(4, 0);
    MFMA_Q(4, 2);

    // epilogue: C[row][col], col=lane&15, row=(lane>>4)*4+j (verified mapping)
    const float sc = *scale_p;
    const int orow0 = tileRow * 256 + wr * 128 + ((lane >> 4) << 2);
    const int ocol0 = tileCol * 256 + wc * 64 + (lane & 15);
    #pragma unroll
    for (int m = 0; m < 8; ++m)
        #pragma unroll
        for (int n = 0; n < 4; ++n)
            #pragma unroll
            for (int j = 0; j < 4; ++j)
                out[(size_t)(orow0 + m * 16 + j) * N_DIM + (ocol0 + n * 16)] = acc[m][n][j] * sc;

#undef LD8
#undef STAGE
#undef READS_FIRST
#undef READS_SECOND
#undef MFMA_Q
}

// ---------------- launch ----------------
extern "C" void kernel_launch(void* const* d_in, const int* in_sizes, int n_in,
                              void* d_out, int out_size, void* d_ws, size_t ws_size,
                              hipStream_t stream) {
    const float* x = (const float*)d_in[0];
    const float* w = (const float*)d_in[1];
    float* out = (float*)d_out;
    uint8_t* ws = (uint8_t*)d_ws;

    float* part  = (float*)ws;                       // 1024 floats
    float* scale = (float*)(ws + 4096);              // 1 float
    unsigned short* Xb = (unsigned short*)(ws + 8192);
    unsigned short* Wb = (unsigned short*)(ws + 8192 + 33554432ull);

    (void)hipFuncSetAttribute((const void*)k_gemm,
                              hipFuncAttributeMaxDynamicSharedMemorySize, 131072);

    hipLaunchKernelGGL(k_abs_part, dim3(1024), dim3(256), 0, stream, (const float4*)w, part);
    hipLaunchKernelGGL(k_abs_final, dim3(1), dim3(256), 0, stream, part, scale);
    hipLaunchKernelGGL(k_prep, dim3(4096), dim3(256), 0, stream,
                       (const float4*)w, (const float4*)x, scale, (uint2*)Wb, (uint2*)Xb);
    hipLaunchKernelGGL(k_gemm, dim3(1024), dim3(512), 131072, stream, Xb, Wb, scale, out);
}